// Round 10
// baseline (259.682 us; speedup 1.0000x reference)
//
#include <hip/hip_runtime.h>

#define N_NODES 20000
#define N_EDGES 320000
#define N_GRAPHS 128
#define IN_DIM 128
#define HDIM 256
#define LAYERS 4
#define EPSV 1e-5f
#define PCH 16
#define ELLS 64                  // ELL stride (max degree; P(deg>64) ~ 4e-14)
#define NBLK_AGG (N_NODES / 4)

#define XQ (N_NODES * IN_DIM / 4)
#define ENC_N (HDIM * IN_DIM)
#define CONV_N (LAYERS * HDIM * HDIM)
#define BN_N (LAYERS * HDIM)
#define PREP_TOTAL (XQ + ENC_N + CONV_N + BN_N + N_NODES)

typedef unsigned short u16;
typedef __attribute__((ext_vector_type(8))) __bf16 bf16x8;
typedef __attribute__((ext_vector_type(4))) float f32x4;
typedef __attribute__((ext_vector_type(8))) unsigned short u16x8;

__device__ __forceinline__ u16 f2bf(float f) {
    unsigned int u = __float_as_uint(f);
    u += 0x7FFFu + ((u >> 16) & 1u);
    return (u16)(u >> 16);
}
__device__ __forceinline__ float bf2f(u16 s) {
    return __uint_as_float((unsigned int)s << 16);
}

// ---------------- fused prep: cvt x / encT / convT, BN fold, zero cnt ----------------
__global__ __launch_bounds__(256) void k_prep(
    const float* __restrict__ x, u16* __restrict__ xb,
    const float* __restrict__ enc_w, u16* __restrict__ encT,
    const float* __restrict__ conv_w, u16* __restrict__ convT,
    const float* __restrict__ gamma, const float* __restrict__ beta,
    const float* __restrict__ mean, const float* __restrict__ var,
    float* __restrict__ bnA, float* __restrict__ bnB, int* __restrict__ cnt)
{
    int idx = blockIdx.x * 256 + threadIdx.x;
    if (idx < XQ) {
        float4 v = *reinterpret_cast<const float4*>(x + (size_t)idx * 4);
        ushort4 o;
        o.x = f2bf(v.x); o.y = f2bf(v.y); o.z = f2bf(v.z); o.w = f2bf(v.w);
        *reinterpret_cast<ushort4*>(xb + (size_t)idx * 4) = o;
        return;
    }
    idx -= XQ;
    if (idx < ENC_N) {
        int n = idx / IN_DIM, k = idx - n * IN_DIM;
        encT[idx] = f2bf(enc_w[(size_t)k * HDIM + n]);
        return;
    }
    idx -= ENC_N;
    if (idx < CONV_N) {
        int l = idx >> 16, i = idx & 65535;
        int n = i >> 8, k = i & 255;
        convT[idx] = f2bf(conv_w[((size_t)l << 16) + (size_t)k * HDIM + n]);
        return;
    }
    idx -= CONV_N;
    if (idx < BN_N) {
        float A = gamma[idx] * rsqrtf(var[idx] + EPSV);
        bnA[idx] = A;
        bnB[idx] = beta[idx] - mean[idx] * A;
        return;
    }
    idx -= BN_N;
    if (idx < N_NODES) cnt[idx] = 0;
}

// ---------------- ELL build: cnt doubles as cursor ----------------
__global__ void k_scatter_ell(const int* __restrict__ src, const int* __restrict__ dst,
                              int* __restrict__ cnt, int* __restrict__ col) {
    int e = blockIdx.x * 256 + threadIdx.x;
    if (e < N_EDGES) {
        int d = dst[e];
        int s = src[e];
        int p = atomicAdd(&cnt[d], 1);
        if (p < ELLS) col[(size_t)d * ELLS + p] = s;
    }
}

__global__ void k_dinv(const int* __restrict__ cnt, float* __restrict__ dinv) {
    int i = blockIdx.x * 256 + threadIdx.x;
    if (i < N_NODES) dinv[i] = rsqrtf((float)cnt[i] + 1.0f);
}

// ---------------- bf16 MFMA GEMM (128x128, 2-phase counted-vmcnt pipeline) ----------------
// Raw s_barrier is NOT a compiler memory fence (LLVM IntrNoMem): pin with
// sched_barrier(0) on both sides so ds_reads can't hoist above the barrier
// and stage loads can't sink/hoist across it (guide rule #18, m201 template).
__device__ __forceinline__ bf16x8 load_frag(const u16* __restrict__ lds, int r, int g) {
    const char* rb = (const char*)(lds + r * 32);
    int s = (r & 3) << 4;
    union { struct { unsigned long long lo, hi; } q; bf16x8 v; } u;
    u.q.lo = *(const unsigned long long*)(rb + ((g * 8) ^ s));
    u.q.hi = *(const unsigned long long*)(rb + ((32 + g * 8) ^ s));
    return u.v;
}

template <int K, int MODE>  // MODE 0: fp32 C (+bias) AND bf16 Cb; MODE 1: bf16 Cb only
__global__ __launch_bounds__(256) void k_gemm_mfma(
    const u16* __restrict__ A, const u16* __restrict__ BT,
    const float* __restrict__ bias, float* __restrict__ C,
    u16* __restrict__ Cb, int M)
{
    constexpr int NT = K / 32;
    __shared__ u16 As[2][128 * 32];
    __shared__ u16 Bs[2][128 * 32];
    const int tid = threadIdx.x;
    const int lane = tid & 63;
    const int wv = tid >> 6, wr = wv >> 1, wc = wv & 1;
    const int m0 = blockIdx.x * 128, n0 = blockIdx.y * 128;
    const int g = lane >> 4, lr = lane & 15;

    f32x4 acc[4][4] = {};

    // stage: 4 global_load_lds wave-instructions -> vmcnt unit = 4
    auto stage = [&](int buf, int k0) {
        #pragma unroll
        for (int j = 0; j < 2; j++) {
            int q = tid + 256 * j;
            int r = q >> 2, c4 = q & 3;
            int boff = (c4 * 16) ^ ((r & 3) << 4);
            int arow = m0 + r; if (arow >= M) arow = M - 1;
            const char* ga = (const char*)(A + (size_t)arow * K + k0) + boff;
            const char* gb = (const char*)(BT + (size_t)(n0 + r) * K + k0) + boff;
            __builtin_amdgcn_global_load_lds(
                (const __attribute__((address_space(1))) void*)ga,
                (__attribute__((address_space(3))) void*)((char*)As[buf] + q * 16), 16, 0, 0);
            __builtin_amdgcn_global_load_lds(
                (const __attribute__((address_space(1))) void*)gb,
                (__attribute__((address_space(3))) void*)((char*)Bs[buf] + q * 16), 16, 0, 0);
        }
    };

    stage(0, 0);
    #pragma unroll
    for (int kt = 0; kt < NT; kt++) {
        const int cur = kt & 1;
        if (kt + 1 < NT) {
            stage(cur ^ 1, (kt + 1) * 32);          // next tile's loads stay in flight
            asm volatile("s_waitcnt vmcnt(4)" ::: "memory");   // cur tile landed (per wave)
        } else {
            asm volatile("s_waitcnt vmcnt(0)" ::: "memory");
        }
        __builtin_amdgcn_sched_barrier(0);
        __builtin_amdgcn_s_barrier();               // all waves: cur buf ready
        __builtin_amdgcn_sched_barrier(0);

        bf16x8 af[4], bfr[4];
        #pragma unroll
        for (int mi = 0; mi < 4; mi++) af[mi] = load_frag(As[cur], wr * 64 + mi * 16 + lr, g);
        #pragma unroll
        for (int ni = 0; ni < 4; ni++) bfr[ni] = load_frag(Bs[cur], wc * 64 + ni * 16 + lr, g);
        #pragma unroll
        for (int mi = 0; mi < 4; mi++)
            #pragma unroll
            for (int ni = 0; ni < 4; ni++)
                acc[mi][ni] = __builtin_amdgcn_mfma_f32_16x16x32_bf16(
                    af[mi], bfr[ni], acc[mi][ni], 0, 0, 0);

        asm volatile("s_waitcnt lgkmcnt(0)" ::: "memory");  // LDS reads retired
        __builtin_amdgcn_sched_barrier(0);
        __builtin_amdgcn_s_barrier();               // reads done before buf overwrite
        __builtin_amdgcn_sched_barrier(0);
    }

    #pragma unroll
    for (int mi = 0; mi < 4; mi++) {
        #pragma unroll
        for (int rg = 0; rg < 4; rg++) {
            int row = m0 + wr * 64 + mi * 16 + g * 4 + rg;
            if (row >= M) continue;
            #pragma unroll
            for (int ni = 0; ni < 4; ni++) {
                int colg = n0 + wc * 64 + ni * 16 + lr;
                float v = acc[mi][ni][rg];
                if (MODE == 0) {
                    v += bias[colg];
                    C[(size_t)row * HDIM + colg] = v;
                }
                Cb[(size_t)row * HDIM + colg] = f2bf(v);
            }
        }
    }
}

// ---------------- aggregate + bias + relu + bn + residual (ELL, fp32 residual) ----------------
__global__ __launch_bounds__(256) void k_aggregate(
    const u16* __restrict__ mb, const float* __restrict__ dinv,
    const int* __restrict__ cnt, const int* __restrict__ col,
    const float* __restrict__ cb, const float* __restrict__ bnA,
    const float* __restrict__ bnB,
    float* __restrict__ h, u16* __restrict__ hb)
{
    const int node = blockIdx.x * 4 + (threadIdx.x >> 6);
    const int lane = threadIdx.x & 63;
    const int p = lane >> 5;
    const int c = (lane & 31) * 8;           // 8 cols (16 B) per lane
    const float di = dinv[node];
    int nb = cnt[node]; if (nb > ELLS) nb = ELLS;

    int s_l = 0; float w_l = 0.f;            // lanes >= nb: row 0, weight 0
    if (lane < nb) {
        s_l = col[(size_t)node * ELLS + lane];
        w_l = dinv[s_l] * di;
    }

    float a[8] = {};
    if (p == 0) {  // self-loop, weight di*di
        float dii = di * di;
        u16x8 v = *reinterpret_cast<const u16x8*>(mb + (size_t)node * HDIM + c);
        #pragma unroll
        for (int j = 0; j < 8; j++) a[j] = dii * bf2f(v[j]);
    }

    const int iters = (nb + 1) >> 1;         // edge pairs (<= 32)
    for (int t = 0; t < iters; t += 8) {
        int e = 2 * t + p;
        int   s0 = __shfl(s_l, e,      64); float w0 = __shfl(w_l, e,      64);
        int   s1 = __shfl(s_l, e + 2,  64); float w1 = __shfl(w_l, e + 2,  64);
        int   s2 = __shfl(s_l, e + 4,  64); float w2 = __shfl(w_l, e + 4,  64);
        int   s3 = __shfl(s_l, e + 6,  64); float w3 = __shfl(w_l, e + 6,  64);
        int   s4 = __shfl(s_l, e + 8,  64); float w4 = __shfl(w_l, e + 8,  64);
        int   s5 = __shfl(s_l, e + 10, 64); float w5 = __shfl(w_l, e + 10, 64);
        int   s6 = __shfl(s_l, e + 12, 64); float w6 = __shfl(w_l, e + 12, 64);
        int   s7 = __shfl(s_l, e + 14, 64); float w7 = __shfl(w_l, e + 14, 64);
        u16x8 v0 = *reinterpret_cast<const u16x8*>(mb + (size_t)s0 * HDIM + c);
        u16x8 v1 = *reinterpret_cast<const u16x8*>(mb + (size_t)s1 * HDIM + c);
        u16x8 v2 = *reinterpret_cast<const u16x8*>(mb + (size_t)s2 * HDIM + c);
        u16x8 v3 = *reinterpret_cast<const u16x8*>(mb + (size_t)s3 * HDIM + c);
        u16x8 v4 = *reinterpret_cast<const u16x8*>(mb + (size_t)s4 * HDIM + c);
        u16x8 v5 = *reinterpret_cast<const u16x8*>(mb + (size_t)s5 * HDIM + c);
        u16x8 v6 = *reinterpret_cast<const u16x8*>(mb + (size_t)s6 * HDIM + c);
        u16x8 v7 = *reinterpret_cast<const u16x8*>(mb + (size_t)s7 * HDIM + c);
        #pragma unroll
        for (int j = 0; j < 8; j++) {
            a[j] += w0 * bf2f(v0[j]) + w1 * bf2f(v1[j]);
            a[j] += w2 * bf2f(v2[j]) + w3 * bf2f(v3[j]);
            a[j] += w4 * bf2f(v4[j]) + w5 * bf2f(v5[j]);
            a[j] += w6 * bf2f(v6[j]) + w7 * bf2f(v7[j]);
        }
    }

    #pragma unroll
    for (int j = 0; j < 8; j++) a[j] += __shfl_xor(a[j], 32, 64);

    if (p == 0) {
        const size_t base = (size_t)node * HDIM + c;
        float4 h0 = *reinterpret_cast<const float4*>(h + base);
        float4 h1 = *reinterpret_cast<const float4*>(h + base + 4);
        float4 cb0 = *reinterpret_cast<const float4*>(cb + c);
        float4 cb1 = *reinterpret_cast<const float4*>(cb + c + 4);
        float4 A0 = *reinterpret_cast<const float4*>(bnA + c);
        float4 A1 = *reinterpret_cast<const float4*>(bnA + c + 4);
        float4 B0 = *reinterpret_cast<const float4*>(bnB + c);
        float4 B1 = *reinterpret_cast<const float4*>(bnB + c + 4);
        float hv[8] = {h0.x, h0.y, h0.z, h0.w, h1.x, h1.y, h1.z, h1.w};
        float cbv[8] = {cb0.x, cb0.y, cb0.z, cb0.w, cb1.x, cb1.y, cb1.z, cb1.w};
        float Av[8] = {A0.x, A0.y, A0.z, A0.w, A1.x, A1.y, A1.z, A1.w};
        float Bv[8] = {B0.x, B0.y, B0.z, B0.w, B1.x, B1.y, B1.z, B1.w};
        float hn[8];
        u16x8 hbv;
        #pragma unroll
        for (int j = 0; j < 8; j++) {
            float v = fmaxf(a[j] + cbv[j], 0.f);
            hn[j] = hv[j] + v * Av[j] + Bv[j];
            hbv[j] = f2bf(hn[j]);
        }
        float4 o0, o1;
        o0.x = hn[0]; o0.y = hn[1]; o0.z = hn[2]; o0.w = hn[3];
        o1.x = hn[4]; o1.y = hn[5]; o1.z = hn[6]; o1.w = hn[7];
        *reinterpret_cast<float4*>(h + base) = o0;
        *reinterpret_cast<float4*>(h + base + 4) = o1;
        *reinterpret_cast<u16x8*>(hb + base) = hbv;
    }
}

// ---------------- pooling: stage 1 partial sums ----------------
__device__ __forceinline__ int lower_bound_dev(const int* a, int n, int key) {
    int lo = 0, hi = n;
    while (lo < hi) {
        int mid = (lo + hi) >> 1;
        if (a[mid] < key) lo = mid + 1; else hi = mid;
    }
    return lo;
}

__global__ __launch_bounds__(256) void k_pool_partial(const float* __restrict__ h,
                                                      const int* __restrict__ batch,
                                                      float* __restrict__ pbuf) {
    int g = blockIdx.x / PCH, c = blockIdx.x % PCH;
    int t = threadIdx.x;
    int start = lower_bound_dev(batch, N_NODES, g);
    int end = lower_bound_dev(batch, N_NODES, g + 1);
    int len = end - start;
    int s0 = start + (int)(((long long)len * c) / PCH);
    int s1 = start + (int)(((long long)len * (c + 1)) / PCH);
    float acc = 0.f;
    for (int n = s0; n < s1; n++) acc += h[(size_t)n * HDIM + t];
    pbuf[(size_t)blockIdx.x * HDIM + t] = acc;
}

// ---------------- head ----------------
__global__ __launch_bounds__(256) void k_head(const float* __restrict__ pbuf,
                                              const int* __restrict__ batch,
                                              const float* __restrict__ w1,
                                              const float* __restrict__ b1,
                                              const float* __restrict__ w2,
                                              const float* __restrict__ b2,
                                              float* __restrict__ out) {
    int g = blockIdx.x;
    int t = threadIdx.x;
    __shared__ float gs[512];
    __shared__ float red[256];
    float s = 0.f;
    #pragma unroll
    for (int c = 0; c < PCH; c++) s += pbuf[(size_t)(g * PCH + c) * HDIM + t];
    int start = lower_bound_dev(batch, N_NODES, g);
    int end = lower_bound_dev(batch, N_NODES, g + 1);
    float cntf = fmaxf((float)(end - start), 1.0f);
    gs[t] = s / cntf;
    gs[256 + t] = s;
    __syncthreads();
    float acc = b1[t];
    for (int k = 0; k < 512; k++) acc += gs[k] * w1[(size_t)k * HDIM + t];
    acc = fmaxf(acc, 0.f);
    red[t] = acc * w2[t];
    __syncthreads();
    for (int s2 = 128; s2 > 0; s2 >>= 1) {
        if (t < s2) red[t] += red[t + s2];
        __syncthreads();
    }
    if (t == 0) out[g] = red[0] + b2[0];
}

extern "C" void kernel_launch(void* const* d_in, const int* in_sizes, int n_in,
                              void* d_out, int out_size, void* d_ws, size_t ws_size,
                              hipStream_t stream) {
    const float* x      = (const float*)d_in[0];
    const int*   ei     = (const int*)d_in[1];
    const int*   srcIdx = ei;
    const int*   dstIdx = ei + N_EDGES;
    const int*   batch  = (const int*)d_in[2];
    const float* enc_w  = (const float*)d_in[3];
    const float* enc_b  = (const float*)d_in[4];
    const float* conv_w = (const float*)d_in[5];
    const float* conv_b = (const float*)d_in[6];
    const float* gamma  = (const float*)d_in[7];
    const float* beta   = (const float*)d_in[8];
    const float* bmean  = (const float*)d_in[9];
    const float* bvar   = (const float*)d_in[10];
    const float* w1     = (const float*)d_in[11];
    const float* b1     = (const float*)d_in[12];
    const float* w2     = (const float*)d_in[13];
    const float* b2     = (const float*)d_in[14];
    float* out = (float*)d_out;

    char* ws = (char*)d_ws;
    size_t off = 0;
    auto alloc = [&](size_t bytes) -> void* {
        void* p = ws + off;
        off = (off + bytes + 255) & ~(size_t)255;
        return p;
    };
    int*   cnt    = (int*)alloc((size_t)N_NODES * 4);
    int*   col    = (int*)alloc((size_t)N_NODES * ELLS * 4);
    float* dinv   = (float*)alloc((size_t)N_NODES * 4);
    float* h      = (float*)alloc((size_t)N_NODES * HDIM * 4);
    u16*   hb     = (u16*)alloc((size_t)N_NODES * HDIM * 2);
    u16*   mb     = (u16*)alloc((size_t)N_NODES * HDIM * 2);
    u16*   encT   = (u16*)alloc((size_t)HDIM * IN_DIM * 2);
    u16*   convT  = (u16*)alloc((size_t)LAYERS * HDIM * HDIM * 2);
    float* bnA    = (float*)alloc((size_t)LAYERS * HDIM * 4);
    float* bnB    = (float*)alloc((size_t)LAYERS * HDIM * 4);
    float* pbuf   = (float*)alloc((size_t)N_GRAPHS * PCH * HDIM * 4);
    u16*   xb     = mb;  // xb consumed by encoder GEMM before mb is written

    const int nb_edges = (N_EDGES + 255) / 256;

    // prep (conversions + BN fold + cnt zero)
    k_prep<<<(PREP_TOTAL + 255) / 256, 256, 0, stream>>>(
        x, xb, enc_w, encT, conv_w, convT, gamma, beta, bmean, bvar, bnA, bnB, cnt);

    // ELL adjacency (cnt doubles as cursor) + dinv
    k_scatter_ell<<<nb_edges, 256, 0, stream>>>(srcIdx, dstIdx, cnt, col);
    k_dinv<<<(N_NODES + 255) / 256, 256, 0, stream>>>(cnt, dinv);

    // encoder -> h fp32 + hb bf16
    dim3 gg((N_NODES + 127) / 128, HDIM / 128);
    k_gemm_mfma<IN_DIM, 0><<<gg, 256, 0, stream>>>(xb, encT, enc_b, h, hb, N_NODES);

    // conv layers
    for (int l = 0; l < LAYERS; l++) {
        k_gemm_mfma<HDIM, 1><<<gg, 256, 0, stream>>>(
            hb, convT + (size_t)l * HDIM * HDIM, nullptr, nullptr, mb, N_NODES);
        k_aggregate<<<NBLK_AGG, 256, 0, stream>>>(
            mb, dinv, cnt, col,
            conv_b + (size_t)l * HDIM, bnA + (size_t)l * HDIM, bnB + (size_t)l * HDIM,
            h, hb);
    }

    // pooling + head
    k_pool_partial<<<N_GRAPHS * PCH, 256, 0, stream>>>(h, batch, pbuf);
    k_head<<<N_GRAPHS, 256, 0, stream>>>(pbuf, batch, w1, b1, w2, b2, out);
}

// Round 11
// 243.364 us; speedup vs baseline: 1.0671x; 1.0671x over previous
//
#include <hip/hip_runtime.h>

#define N_NODES 20000
#define N_EDGES 320000
#define N_GRAPHS 128
#define IN_DIM 128
#define HDIM 256
#define LAYERS 4
#define EPSV 1e-5f
#define PCH 16
#define ELLS 64                  // ELL stride (max degree; P(deg>64) ~ 4e-14)
#define NBLK_AGG (N_NODES / 4)

#define XQ (N_NODES * IN_DIM / 4)
#define ENC_N (HDIM * IN_DIM)
#define CONV_N (LAYERS * HDIM * HDIM)
#define BN_N (LAYERS * HDIM)
#define PREP_TOTAL (XQ + ENC_N + CONV_N + BN_N + N_NODES)

typedef unsigned short u16;
typedef __attribute__((ext_vector_type(8))) __bf16 bf16x8;
typedef __attribute__((ext_vector_type(4))) float f32x4;
typedef __attribute__((ext_vector_type(8))) unsigned short u16x8;

__device__ __forceinline__ u16 f2bf(float f) {
    unsigned int u = __float_as_uint(f);
    u += 0x7FFFu + ((u >> 16) & 1u);
    return (u16)(u >> 16);
}
__device__ __forceinline__ float bf2f(u16 s) {
    return __uint_as_float((unsigned int)s << 16);
}

// ---------------- fused prep: cvt x / encT / convT, BN fold, zero cnt ----------------
__global__ __launch_bounds__(256) void k_prep(
    const float* __restrict__ x, u16* __restrict__ xb,
    const float* __restrict__ enc_w, u16* __restrict__ encT,
    const float* __restrict__ conv_w, u16* __restrict__ convT,
    const float* __restrict__ gamma, const float* __restrict__ beta,
    const float* __restrict__ mean, const float* __restrict__ var,
    float* __restrict__ bnA, float* __restrict__ bnB, int* __restrict__ cnt)
{
    int idx = blockIdx.x * 256 + threadIdx.x;
    if (idx < XQ) {
        float4 v = *reinterpret_cast<const float4*>(x + (size_t)idx * 4);
        ushort4 o;
        o.x = f2bf(v.x); o.y = f2bf(v.y); o.z = f2bf(v.z); o.w = f2bf(v.w);
        *reinterpret_cast<ushort4*>(xb + (size_t)idx * 4) = o;
        return;
    }
    idx -= XQ;
    if (idx < ENC_N) {
        int n = idx / IN_DIM, k = idx - n * IN_DIM;
        encT[idx] = f2bf(enc_w[(size_t)k * HDIM + n]);
        return;
    }
    idx -= ENC_N;
    if (idx < CONV_N) {
        int l = idx >> 16, i = idx & 65535;
        int n = i >> 8, k = i & 255;
        convT[idx] = f2bf(conv_w[((size_t)l << 16) + (size_t)k * HDIM + n]);
        return;
    }
    idx -= CONV_N;
    if (idx < BN_N) {
        float A = gamma[idx] * rsqrtf(var[idx] + EPSV);
        bnA[idx] = A;
        bnB[idx] = beta[idx] - mean[idx] * A;
        return;
    }
    idx -= BN_N;
    if (idx < N_NODES) cnt[idx] = 0;
}

// ---------------- ELL build: cnt doubles as cursor ----------------
__global__ void k_scatter_ell(const int* __restrict__ src, const int* __restrict__ dst,
                              int* __restrict__ cnt, int* __restrict__ col) {
    int e = blockIdx.x * 256 + threadIdx.x;
    if (e < N_EDGES) {
        int d = dst[e];
        int s = src[e];
        int p = atomicAdd(&cnt[d], 1);
        if (p < ELLS) col[(size_t)d * ELLS + p] = s;
    }
}

// ---------------- bf16 MFMA GEMM (128x128, 2-phase counted-vmcnt pipeline) ----------------
// Raw s_barrier is NOT a compiler memory fence (LLVM IntrNoMem): pin with
// sched_barrier(0) on both sides (guide rule #18) — verified R10.
__device__ __forceinline__ bf16x8 load_frag(const u16* __restrict__ lds, int r, int g) {
    const char* rb = (const char*)(lds + r * 32);
    int s = (r & 3) << 4;
    union { struct { unsigned long long lo, hi; } q; bf16x8 v; } u;
    u.q.lo = *(const unsigned long long*)(rb + ((g * 8) ^ s));
    u.q.hi = *(const unsigned long long*)(rb + ((32 + g * 8) ^ s));
    return u.v;
}

template <int K, int MODE>  // MODE 0: +bias (encoder); MODE 1: plain. bf16 output only.
__global__ __launch_bounds__(256) void k_gemm_mfma(
    const u16* __restrict__ A, const u16* __restrict__ BT,
    const float* __restrict__ bias, u16* __restrict__ Cb, int M)
{
    constexpr int NT = K / 32;
    __shared__ u16 As[2][128 * 32];
    __shared__ u16 Bs[2][128 * 32];
    const int tid = threadIdx.x;
    const int lane = tid & 63;
    const int wv = tid >> 6, wr = wv >> 1, wc = wv & 1;
    const int m0 = blockIdx.x * 128, n0 = blockIdx.y * 128;
    const int g = lane >> 4, lr = lane & 15;

    f32x4 acc[4][4] = {};

    // stage: 4 global_load_lds wave-instructions -> vmcnt unit = 4
    auto stage = [&](int buf, int k0) {
        #pragma unroll
        for (int j = 0; j < 2; j++) {
            int q = tid + 256 * j;
            int r = q >> 2, c4 = q & 3;
            int boff = (c4 * 16) ^ ((r & 3) << 4);
            int arow = m0 + r; if (arow >= M) arow = M - 1;
            const char* ga = (const char*)(A + (size_t)arow * K + k0) + boff;
            const char* gb = (const char*)(BT + (size_t)(n0 + r) * K + k0) + boff;
            __builtin_amdgcn_global_load_lds(
                (const __attribute__((address_space(1))) void*)ga,
                (__attribute__((address_space(3))) void*)((char*)As[buf] + q * 16), 16, 0, 0);
            __builtin_amdgcn_global_load_lds(
                (const __attribute__((address_space(1))) void*)gb,
                (__attribute__((address_space(3))) void*)((char*)Bs[buf] + q * 16), 16, 0, 0);
        }
    };

    stage(0, 0);
    #pragma unroll
    for (int kt = 0; kt < NT; kt++) {
        const int cur = kt & 1;
        if (kt + 1 < NT) {
            stage(cur ^ 1, (kt + 1) * 32);          // next tile's loads stay in flight
            asm volatile("s_waitcnt vmcnt(4)" ::: "memory");   // cur tile landed (per wave)
        } else {
            asm volatile("s_waitcnt vmcnt(0)" ::: "memory");
        }
        __builtin_amdgcn_sched_barrier(0);
        __builtin_amdgcn_s_barrier();               // all waves: cur buf ready
        __builtin_amdgcn_sched_barrier(0);

        bf16x8 af[4], bfr[4];
        #pragma unroll
        for (int mi = 0; mi < 4; mi++) af[mi] = load_frag(As[cur], wr * 64 + mi * 16 + lr, g);
        #pragma unroll
        for (int ni = 0; ni < 4; ni++) bfr[ni] = load_frag(Bs[cur], wc * 64 + ni * 16 + lr, g);
        #pragma unroll
        for (int mi = 0; mi < 4; mi++)
            #pragma unroll
            for (int ni = 0; ni < 4; ni++)
                acc[mi][ni] = __builtin_amdgcn_mfma_f32_16x16x32_bf16(
                    af[mi], bfr[ni], acc[mi][ni], 0, 0, 0);

        asm volatile("s_waitcnt lgkmcnt(0)" ::: "memory");  // LDS reads retired
        __builtin_amdgcn_sched_barrier(0);
        __builtin_amdgcn_s_barrier();               // reads done before buf overwrite
        __builtin_amdgcn_sched_barrier(0);
    }

    #pragma unroll
    for (int mi = 0; mi < 4; mi++) {
        #pragma unroll
        for (int rg = 0; rg < 4; rg++) {
            int row = m0 + wr * 64 + mi * 16 + g * 4 + rg;
            if (row >= M) continue;
            #pragma unroll
            for (int ni = 0; ni < 4; ni++) {
                int colg = n0 + wc * 64 + ni * 16 + lr;
                float v = acc[mi][ni][rg];
                if (MODE == 0) v += bias[colg];
                Cb[(size_t)row * HDIM + colg] = f2bf(v);
            }
        }
    }
}

// ---------------- aggregate + bias + relu + bn + residual (ELL, bf16 chain) ----------------
// dinv computed on the fly from cnt (rsqrt is cheap; same gather traffic).
// WRITEH=0: residual chain in bf16, hb updated in place.
// WRITEH=1 (last layer): write fp32 h for pooling.
template <int WRITEH>
__global__ __launch_bounds__(256) void k_aggregate(
    const u16* __restrict__ mb, const int* __restrict__ cnt,
    const int* __restrict__ col,
    const float* __restrict__ cb, const float* __restrict__ bnA,
    const float* __restrict__ bnB,
    float* __restrict__ h, u16* __restrict__ hb)
{
    const int node = blockIdx.x * 4 + (threadIdx.x >> 6);
    const int lane = threadIdx.x & 63;
    const int p = lane >> 5;
    const int c = (lane & 31) * 8;           // 8 cols (16 B) per lane
    int nb = cnt[node]; if (nb > ELLS) nb = ELLS;
    const float di = rsqrtf((float)nb + 1.0f);

    int s_l = 0; float w_l = 0.f;            // lanes >= nb: row 0, weight 0
    if (lane < nb) {
        s_l = col[(size_t)node * ELLS + lane];
        w_l = rsqrtf((float)cnt[s_l] + 1.0f) * di;
    }

    float a[8] = {};
    if (p == 0) {  // self-loop, weight di*di
        float dii = di * di;
        u16x8 v = *reinterpret_cast<const u16x8*>(mb + (size_t)node * HDIM + c);
        #pragma unroll
        for (int j = 0; j < 8; j++) a[j] = dii * bf2f(v[j]);
    }

    const int iters = (nb + 1) >> 1;         // edge pairs (<= 32)
    for (int t = 0; t < iters; t += 8) {
        int e = 2 * t + p;
        int   s0 = __shfl(s_l, e,      64); float w0 = __shfl(w_l, e,      64);
        int   s1 = __shfl(s_l, e + 2,  64); float w1 = __shfl(w_l, e + 2,  64);
        int   s2 = __shfl(s_l, e + 4,  64); float w2 = __shfl(w_l, e + 4,  64);
        int   s3 = __shfl(s_l, e + 6,  64); float w3 = __shfl(w_l, e + 6,  64);
        int   s4 = __shfl(s_l, e + 8,  64); float w4 = __shfl(w_l, e + 8,  64);
        int   s5 = __shfl(s_l, e + 10, 64); float w5 = __shfl(w_l, e + 10, 64);
        int   s6 = __shfl(s_l, e + 12, 64); float w6 = __shfl(w_l, e + 12, 64);
        int   s7 = __shfl(s_l, e + 14, 64); float w7 = __shfl(w_l, e + 14, 64);
        u16x8 v0 = *reinterpret_cast<const u16x8*>(mb + (size_t)s0 * HDIM + c);
        u16x8 v1 = *reinterpret_cast<const u16x8*>(mb + (size_t)s1 * HDIM + c);
        u16x8 v2 = *reinterpret_cast<const u16x8*>(mb + (size_t)s2 * HDIM + c);
        u16x8 v3 = *reinterpret_cast<const u16x8*>(mb + (size_t)s3 * HDIM + c);
        u16x8 v4 = *reinterpret_cast<const u16x8*>(mb + (size_t)s4 * HDIM + c);
        u16x8 v5 = *reinterpret_cast<const u16x8*>(mb + (size_t)s5 * HDIM + c);
        u16x8 v6 = *reinterpret_cast<const u16x8*>(mb + (size_t)s6 * HDIM + c);
        u16x8 v7 = *reinterpret_cast<const u16x8*>(mb + (size_t)s7 * HDIM + c);
        #pragma unroll
        for (int j = 0; j < 8; j++) {
            a[j] += w0 * bf2f(v0[j]) + w1 * bf2f(v1[j]);
            a[j] += w2 * bf2f(v2[j]) + w3 * bf2f(v3[j]);
            a[j] += w4 * bf2f(v4[j]) + w5 * bf2f(v5[j]);
            a[j] += w6 * bf2f(v6[j]) + w7 * bf2f(v7[j]);
        }
    }

    #pragma unroll
    for (int j = 0; j < 8; j++) a[j] += __shfl_xor(a[j], 32, 64);

    if (p == 0) {
        const size_t base = (size_t)node * HDIM + c;
        u16x8 rv = *reinterpret_cast<const u16x8*>(hb + base);   // residual (bf16)
        float4 cb0 = *reinterpret_cast<const float4*>(cb + c);
        float4 cb1 = *reinterpret_cast<const float4*>(cb + c + 4);
        float4 A0 = *reinterpret_cast<const float4*>(bnA + c);
        float4 A1 = *reinterpret_cast<const float4*>(bnA + c + 4);
        float4 B0 = *reinterpret_cast<const float4*>(bnB + c);
        float4 B1 = *reinterpret_cast<const float4*>(bnB + c + 4);
        float cbv[8] = {cb0.x, cb0.y, cb0.z, cb0.w, cb1.x, cb1.y, cb1.z, cb1.w};
        float Av[8] = {A0.x, A0.y, A0.z, A0.w, A1.x, A1.y, A1.z, A1.w};
        float Bv[8] = {B0.x, B0.y, B0.z, B0.w, B1.x, B1.y, B1.z, B1.w};
        float hn[8];
        #pragma unroll
        for (int j = 0; j < 8; j++) {
            float v = fmaxf(a[j] + cbv[j], 0.f);
            hn[j] = bf2f(rv[j]) + v * Av[j] + Bv[j];
        }
        if (WRITEH) {
            float4 o0, o1;
            o0.x = hn[0]; o0.y = hn[1]; o0.z = hn[2]; o0.w = hn[3];
            o1.x = hn[4]; o1.y = hn[5]; o1.z = hn[6]; o1.w = hn[7];
            *reinterpret_cast<float4*>(h + base) = o0;
            *reinterpret_cast<float4*>(h + base + 4) = o1;
        } else {
            u16x8 hbv;
            #pragma unroll
            for (int j = 0; j < 8; j++) hbv[j] = f2bf(hn[j]);
            *reinterpret_cast<u16x8*>(hb + base) = hbv;
        }
    }
}

// ---------------- pooling: stage 1 partial sums ----------------
__device__ __forceinline__ int lower_bound_dev(const int* a, int n, int key) {
    int lo = 0, hi = n;
    while (lo < hi) {
        int mid = (lo + hi) >> 1;
        if (a[mid] < key) lo = mid + 1; else hi = mid;
    }
    return lo;
}

__global__ __launch_bounds__(256) void k_pool_partial(const float* __restrict__ h,
                                                      const int* __restrict__ batch,
                                                      float* __restrict__ pbuf) {
    int g = blockIdx.x / PCH, c = blockIdx.x % PCH;
    int t = threadIdx.x;
    int start = lower_bound_dev(batch, N_NODES, g);
    int end = lower_bound_dev(batch, N_NODES, g + 1);
    int len = end - start;
    int s0 = start + (int)(((long long)len * c) / PCH);
    int s1 = start + (int)(((long long)len * (c + 1)) / PCH);
    float acc = 0.f;
    for (int n = s0; n < s1; n++) acc += h[(size_t)n * HDIM + t];
    pbuf[(size_t)blockIdx.x * HDIM + t] = acc;
}

// ---------------- head ----------------
__global__ __launch_bounds__(256) void k_head(const float* __restrict__ pbuf,
                                              const int* __restrict__ batch,
                                              const float* __restrict__ w1,
                                              const float* __restrict__ b1,
                                              const float* __restrict__ w2,
                                              const float* __restrict__ b2,
                                              float* __restrict__ out) {
    int g = blockIdx.x;
    int t = threadIdx.x;
    __shared__ float gs[512];
    __shared__ float red[256];
    float s = 0.f;
    #pragma unroll
    for (int c = 0; c < PCH; c++) s += pbuf[(size_t)(g * PCH + c) * HDIM + t];
    int start = lower_bound_dev(batch, N_NODES, g);
    int end = lower_bound_dev(batch, N_NODES, g + 1);
    float cntf = fmaxf((float)(end - start), 1.0f);
    gs[t] = s / cntf;
    gs[256 + t] = s;
    __syncthreads();
    float acc = b1[t];
    for (int k = 0; k < 512; k++) acc += gs[k] * w1[(size_t)k * HDIM + t];
    acc = fmaxf(acc, 0.f);
    red[t] = acc * w2[t];
    __syncthreads();
    for (int s2 = 128; s2 > 0; s2 >>= 1) {
        if (t < s2) red[t] += red[t + s2];
        __syncthreads();
    }
    if (t == 0) out[g] = red[0] + b2[0];
}

extern "C" void kernel_launch(void* const* d_in, const int* in_sizes, int n_in,
                              void* d_out, int out_size, void* d_ws, size_t ws_size,
                              hipStream_t stream) {
    const float* x      = (const float*)d_in[0];
    const int*   ei     = (const int*)d_in[1];
    const int*   srcIdx = ei;
    const int*   dstIdx = ei + N_EDGES;
    const int*   batch  = (const int*)d_in[2];
    const float* enc_w  = (const float*)d_in[3];
    const float* enc_b  = (const float*)d_in[4];
    const float* conv_w = (const float*)d_in[5];
    const float* conv_b = (const float*)d_in[6];
    const float* gamma  = (const float*)d_in[7];
    const float* beta   = (const float*)d_in[8];
    const float* bmean  = (const float*)d_in[9];
    const float* bvar   = (const float*)d_in[10];
    const float* w1     = (const float*)d_in[11];
    const float* b1     = (const float*)d_in[12];
    const float* w2     = (const float*)d_in[13];
    const float* b2     = (const float*)d_in[14];
    float* out = (float*)d_out;

    char* ws = (char*)d_ws;
    size_t off = 0;
    auto alloc = [&](size_t bytes) -> void* {
        void* p = ws + off;
        off = (off + bytes + 255) & ~(size_t)255;
        return p;
    };
    int*   cnt    = (int*)alloc((size_t)N_NODES * 4);
    int*   col    = (int*)alloc((size_t)N_NODES * ELLS * 4);
    float* h      = (float*)alloc((size_t)N_NODES * HDIM * 4);
    u16*   hb     = (u16*)alloc((size_t)N_NODES * HDIM * 2);
    u16*   mb     = (u16*)alloc((size_t)N_NODES * HDIM * 2);
    u16*   encT   = (u16*)alloc((size_t)HDIM * IN_DIM * 2);
    u16*   convT  = (u16*)alloc((size_t)LAYERS * HDIM * HDIM * 2);
    float* bnA    = (float*)alloc((size_t)LAYERS * HDIM * 4);
    float* bnB    = (float*)alloc((size_t)LAYERS * HDIM * 4);
    float* pbuf   = (float*)alloc((size_t)N_GRAPHS * PCH * HDIM * 4);
    u16*   xb     = mb;  // xb consumed by encoder GEMM before mb is written

    const int nb_edges = (N_EDGES + 255) / 256;

    // prep (conversions + BN fold + cnt zero)
    k_prep<<<(PREP_TOTAL + 255) / 256, 256, 0, stream>>>(
        x, xb, enc_w, encT, conv_w, convT, gamma, beta, bmean, bvar, bnA, bnB, cnt);

    // ELL adjacency (cnt doubles as cursor; final value = degree)
    k_scatter_ell<<<nb_edges, 256, 0, stream>>>(srcIdx, dstIdx, cnt, col);

    // encoder -> hb (bf16 residual stream)
    dim3 gg((N_NODES + 127) / 128, HDIM / 128);
    k_gemm_mfma<IN_DIM, 0><<<gg, 256, 0, stream>>>(xb, encT, enc_b, hb, N_NODES);

    // conv layers
    for (int l = 0; l < LAYERS; l++) {
        k_gemm_mfma<HDIM, 1><<<gg, 256, 0, stream>>>(
            hb, convT + (size_t)l * HDIM * HDIM, nullptr, mb, N_NODES);
        if (l < LAYERS - 1)
            k_aggregate<0><<<NBLK_AGG, 256, 0, stream>>>(
                mb, cnt, col,
                conv_b + (size_t)l * HDIM, bnA + (size_t)l * HDIM, bnB + (size_t)l * HDIM,
                h, hb);
        else
            k_aggregate<1><<<NBLK_AGG, 256, 0, stream>>>(
                mb, cnt, col,
                conv_b + (size_t)l * HDIM, bnA + (size_t)l * HDIM, bnB + (size_t)l * HDIM,
                h, hb);
    }

    // pooling + head
    k_pool_partial<<<N_GRAPHS * PCH, 256, 0, stream>>>(h, batch, pbuf);
    k_head<<<N_GRAPHS, 256, 0, stream>>>(pbuf, batch, w1, b1, w2, b2, out);
}

// Round 12
// 230.478 us; speedup vs baseline: 1.1267x; 1.0559x over previous
//
#include <hip/hip_runtime.h>

#define N_NODES 20000
#define N_EDGES 320000
#define N_GRAPHS 128
#define IN_DIM 128
#define HDIM 256
#define LAYERS 4
#define EPSV 1e-5f
#define PCH 16
#define ELLS 64                  // ELL stride (max degree; P(deg>64) ~ 4e-14)
#define NBLK_AGG (N_NODES / 4)

#define XQ (N_NODES * IN_DIM / 4)
#define ENC_N (HDIM * IN_DIM)
#define CONV_N (LAYERS * HDIM * HDIM)
#define BN_N (LAYERS * HDIM)
#define PREP_TOTAL (XQ + ENC_N + CONV_N + BN_N + N_NODES)

typedef unsigned short u16;
typedef __attribute__((ext_vector_type(8))) __bf16 bf16x8;
typedef __attribute__((ext_vector_type(4))) float f32x4;
typedef __attribute__((ext_vector_type(8))) unsigned short u16x8;

__device__ __forceinline__ u16 f2bf(float f) {
    unsigned int u = __float_as_uint(f);
    u += 0x7FFFu + ((u >> 16) & 1u);
    return (u16)(u >> 16);
}
__device__ __forceinline__ float bf2f(u16 s) {
    return __uint_as_float((unsigned int)s << 16);
}

// ---------------- fused prep: cvt x / encT / convT, BN fold, zero cnt ----------------
__global__ __launch_bounds__(256) void k_prep(
    const float* __restrict__ x, u16* __restrict__ xb,
    const float* __restrict__ enc_w, u16* __restrict__ encT,
    const float* __restrict__ conv_w, u16* __restrict__ convT,
    const float* __restrict__ gamma, const float* __restrict__ beta,
    const float* __restrict__ mean, const float* __restrict__ var,
    float* __restrict__ bnA, float* __restrict__ bnB, int* __restrict__ cnt)
{
    int idx = blockIdx.x * 256 + threadIdx.x;
    if (idx < XQ) {
        float4 v = *reinterpret_cast<const float4*>(x + (size_t)idx * 4);
        ushort4 o;
        o.x = f2bf(v.x); o.y = f2bf(v.y); o.z = f2bf(v.z); o.w = f2bf(v.w);
        *reinterpret_cast<ushort4*>(xb + (size_t)idx * 4) = o;
        return;
    }
    idx -= XQ;
    if (idx < ENC_N) {
        int n = idx / IN_DIM, k = idx - n * IN_DIM;
        encT[idx] = f2bf(enc_w[(size_t)k * HDIM + n]);
        return;
    }
    idx -= ENC_N;
    if (idx < CONV_N) {
        int l = idx >> 16, i = idx & 65535;
        int n = i >> 8, k = i & 255;
        convT[idx] = f2bf(conv_w[((size_t)l << 16) + (size_t)k * HDIM + n]);
        return;
    }
    idx -= CONV_N;
    if (idx < BN_N) {
        float A = gamma[idx] * rsqrtf(var[idx] + EPSV);
        bnA[idx] = A;
        bnB[idx] = beta[idx] - mean[idx] * A;
        return;
    }
    idx -= BN_N;
    if (idx < N_NODES) cnt[idx] = 0;
}

// ---------------- ELL build: cnt doubles as cursor ----------------
__global__ void k_scatter_ell(const int* __restrict__ src, const int* __restrict__ dst,
                              int* __restrict__ cnt, int* __restrict__ col) {
    int e = blockIdx.x * 256 + threadIdx.x;
    if (e < N_EDGES) {
        int d = dst[e];
        int s = src[e];
        int p = atomicAdd(&cnt[d], 1);
        if (p < ELLS) col[(size_t)d * ELLS + p] = s;
    }
}

// ---------------- bf16 MFMA GEMM (128x64 tile, BK=64, counted-vmcnt pipeline) ----------------
// Grid 157x4 = 628 blocks @ 48 KB LDS -> 3 blocks/CU -> whole grid co-resident
// (no tail). Raw s_barrier is NOT a compiler memory fence: sched_barrier(0)
// pins on both sides (rule #18, verified R10).
__device__ __forceinline__ bf16x8 load_frag(const u16* __restrict__ lds, int r, int g) {
    const char* rb = (const char*)(lds + r * 32);
    int s = (r & 3) << 4;
    union { struct { unsigned long long lo, hi; } q; bf16x8 v; } u;
    u.q.lo = *(const unsigned long long*)(rb + ((g * 8) ^ s));
    u.q.hi = *(const unsigned long long*)(rb + ((32 + g * 8) ^ s));
    return u.v;
}

template <int K, int MODE>  // MODE 0: +bias (encoder); MODE 1: plain. bf16 output.
__global__ __launch_bounds__(256) void k_gemm_mfma(
    const u16* __restrict__ A, const u16* __restrict__ BT,
    const float* __restrict__ bias, u16* __restrict__ Cb, int M)
{
    constexpr int NT2 = K / 64;              // BK = 64 (two 32-wide sub-tiles)
    __shared__ u16 As[2][2][128 * 32];
    __shared__ u16 Bs[2][2][64 * 32];
    const int tid = threadIdx.x;
    const int lane = tid & 63;
    const int wr = tid >> 6;                 // wave 0..3 -> row quadrant
    const int m0 = blockIdx.x * 128, n0 = blockIdx.y * 64;
    const int g = lane >> 4, lr = lane & 15;

    f32x4 acc[2][4] = {};

    // 6 global_load_lds wave-instructions per stage -> vmcnt unit = 6
    auto stage = [&](int buf, int k0) {
        #pragma unroll
        for (int kk = 0; kk < 2; kk++) {
            #pragma unroll
            for (int j = 0; j < 2; j++) {
                int q = tid + 256 * j;
                int r = q >> 2, c4 = q & 3;
                int boff = (c4 * 16) ^ ((r & 3) << 4);
                int arow = m0 + r; if (arow >= M) arow = M - 1;
                const char* ga = (const char*)(A + (size_t)arow * K + k0 + kk * 32) + boff;
                __builtin_amdgcn_global_load_lds(
                    (const __attribute__((address_space(1))) void*)ga,
                    (__attribute__((address_space(3))) void*)((char*)As[buf][kk] + q * 16),
                    16, 0, 0);
            }
            {
                int q = tid;
                int r = q >> 2, c4 = q & 3;
                int boff = (c4 * 16) ^ ((r & 3) << 4);
                const char* gb = (const char*)(BT + (size_t)(n0 + r) * K + k0 + kk * 32) + boff;
                __builtin_amdgcn_global_load_lds(
                    (const __attribute__((address_space(1))) void*)gb,
                    (__attribute__((address_space(3))) void*)((char*)Bs[buf][kk] + q * 16),
                    16, 0, 0);
            }
        }
    };

    stage(0, 0);
    #pragma unroll
    for (int kt = 0; kt < NT2; kt++) {
        const int cur = kt & 1;
        if (kt + 1 < NT2) {
            stage(cur ^ 1, (kt + 1) * 64);          // next tile's loads stay in flight
            asm volatile("s_waitcnt vmcnt(6)" ::: "memory");   // cur tile landed
        } else {
            asm volatile("s_waitcnt vmcnt(0)" ::: "memory");
        }
        __builtin_amdgcn_sched_barrier(0);
        __builtin_amdgcn_s_barrier();               // all waves: cur buf ready
        __builtin_amdgcn_sched_barrier(0);

        #pragma unroll
        for (int kk = 0; kk < 2; kk++) {
            bf16x8 af[2], bfr[4];
            #pragma unroll
            for (int mi = 0; mi < 2; mi++)
                af[mi] = load_frag(As[cur][kk], wr * 32 + mi * 16 + lr, g);
            #pragma unroll
            for (int ni = 0; ni < 4; ni++)
                bfr[ni] = load_frag(Bs[cur][kk], ni * 16 + lr, g);
            #pragma unroll
            for (int mi = 0; mi < 2; mi++)
                #pragma unroll
                for (int ni = 0; ni < 4; ni++)
                    acc[mi][ni] = __builtin_amdgcn_mfma_f32_16x16x32_bf16(
                        af[mi], bfr[ni], acc[mi][ni], 0, 0, 0);
        }

        asm volatile("s_waitcnt lgkmcnt(0)" ::: "memory");  // LDS reads retired
        __builtin_amdgcn_sched_barrier(0);
        __builtin_amdgcn_s_barrier();               // reads done before buf overwrite
        __builtin_amdgcn_sched_barrier(0);
    }

    #pragma unroll
    for (int mi = 0; mi < 2; mi++) {
        #pragma unroll
        for (int rg = 0; rg < 4; rg++) {
            int row = m0 + wr * 32 + mi * 16 + g * 4 + rg;
            if (row >= M) continue;
            #pragma unroll
            for (int ni = 0; ni < 4; ni++) {
                int colg = n0 + ni * 16 + lr;
                float v = acc[mi][ni][rg];
                if (MODE == 0) v += bias[colg];
                Cb[(size_t)row * HDIM + colg] = f2bf(v);
            }
        }
    }
}

// ---------------- aggregate + bias + relu + bn + residual (ELL, bf16 chain) ----------------
__global__ __launch_bounds__(256) void k_aggregate(
    const u16* __restrict__ mb, const int* __restrict__ cnt,
    const int* __restrict__ col,
    const float* __restrict__ cb, const float* __restrict__ bnA,
    const float* __restrict__ bnB, u16* __restrict__ hb)
{
    const int node = blockIdx.x * 4 + (threadIdx.x >> 6);
    const int lane = threadIdx.x & 63;
    const int p = lane >> 5;
    const int c = (lane & 31) * 8;           // 8 cols (16 B) per lane
    int nb = cnt[node]; if (nb > ELLS) nb = ELLS;
    const float di = rsqrtf((float)nb + 1.0f);

    int s_l = 0; float w_l = 0.f;            // lanes >= nb: row 0, weight 0
    if (lane < nb) {
        s_l = col[(size_t)node * ELLS + lane];
        w_l = rsqrtf((float)cnt[s_l] + 1.0f) * di;
    }

    float a[8] = {};
    if (p == 0) {  // self-loop, weight di*di
        float dii = di * di;
        u16x8 v = *reinterpret_cast<const u16x8*>(mb + (size_t)node * HDIM + c);
        #pragma unroll
        for (int j = 0; j < 8; j++) a[j] = dii * bf2f(v[j]);
    }

    const int iters = (nb + 1) >> 1;         // edge pairs (<= 32)
    for (int t = 0; t < iters; t += 8) {
        int e = 2 * t + p;
        int   s0 = __shfl(s_l, e,      64); float w0 = __shfl(w_l, e,      64);
        int   s1 = __shfl(s_l, e + 2,  64); float w1 = __shfl(w_l, e + 2,  64);
        int   s2 = __shfl(s_l, e + 4,  64); float w2 = __shfl(w_l, e + 4,  64);
        int   s3 = __shfl(s_l, e + 6,  64); float w3 = __shfl(w_l, e + 6,  64);
        int   s4 = __shfl(s_l, e + 8,  64); float w4 = __shfl(w_l, e + 8,  64);
        int   s5 = __shfl(s_l, e + 10, 64); float w5 = __shfl(w_l, e + 10, 64);
        int   s6 = __shfl(s_l, e + 12, 64); float w6 = __shfl(w_l, e + 12, 64);
        int   s7 = __shfl(s_l, e + 14, 64); float w7 = __shfl(w_l, e + 14, 64);
        u16x8 v0 = *reinterpret_cast<const u16x8*>(mb + (size_t)s0 * HDIM + c);
        u16x8 v1 = *reinterpret_cast<const u16x8*>(mb + (size_t)s1 * HDIM + c);
        u16x8 v2 = *reinterpret_cast<const u16x8*>(mb + (size_t)s2 * HDIM + c);
        u16x8 v3 = *reinterpret_cast<const u16x8*>(mb + (size_t)s3 * HDIM + c);
        u16x8 v4 = *reinterpret_cast<const u16x8*>(mb + (size_t)s4 * HDIM + c);
        u16x8 v5 = *reinterpret_cast<const u16x8*>(mb + (size_t)s5 * HDIM + c);
        u16x8 v6 = *reinterpret_cast<const u16x8*>(mb + (size_t)s6 * HDIM + c);
        u16x8 v7 = *reinterpret_cast<const u16x8*>(mb + (size_t)s7 * HDIM + c);
        #pragma unroll
        for (int j = 0; j < 8; j++) {
            a[j] += w0 * bf2f(v0[j]) + w1 * bf2f(v1[j]);
            a[j] += w2 * bf2f(v2[j]) + w3 * bf2f(v3[j]);
            a[j] += w4 * bf2f(v4[j]) + w5 * bf2f(v5[j]);
            a[j] += w6 * bf2f(v6[j]) + w7 * bf2f(v7[j]);
        }
    }

    #pragma unroll
    for (int j = 0; j < 8; j++) a[j] += __shfl_xor(a[j], 32, 64);

    if (p == 0) {
        const size_t base = (size_t)node * HDIM + c;
        u16x8 rv = *reinterpret_cast<const u16x8*>(hb + base);   // residual (bf16)
        float4 cb0 = *reinterpret_cast<const float4*>(cb + c);
        float4 cb1 = *reinterpret_cast<const float4*>(cb + c + 4);
        float4 A0 = *reinterpret_cast<const float4*>(bnA + c);
        float4 A1 = *reinterpret_cast<const float4*>(bnA + c + 4);
        float4 B0 = *reinterpret_cast<const float4*>(bnB + c);
        float4 B1 = *reinterpret_cast<const float4*>(bnB + c + 4);
        float cbv[8] = {cb0.x, cb0.y, cb0.z, cb0.w, cb1.x, cb1.y, cb1.z, cb1.w};
        float Av[8] = {A0.x, A0.y, A0.z, A0.w, A1.x, A1.y, A1.z, A1.w};
        float Bv[8] = {B0.x, B0.y, B0.z, B0.w, B1.x, B1.y, B1.z, B1.w};
        u16x8 hbv;
        #pragma unroll
        for (int j = 0; j < 8; j++) {
            float v = fmaxf(a[j] + cbv[j], 0.f);
            hbv[j] = f2bf(bf2f(rv[j]) + v * Av[j] + Bv[j]);
        }
        *reinterpret_cast<u16x8*>(hb + base) = hbv;
    }
}

// ---------------- pooling: stage 1 partial sums (bf16 input) ----------------
__device__ __forceinline__ int lower_bound_dev(const int* a, int n, int key) {
    int lo = 0, hi = n;
    while (lo < hi) {
        int mid = (lo + hi) >> 1;
        if (a[mid] < key) lo = mid + 1; else hi = mid;
    }
    return lo;
}

__global__ __launch_bounds__(256) void k_pool_partial(const u16* __restrict__ hb,
                                                      const int* __restrict__ batch,
                                                      float* __restrict__ pbuf) {
    int g = blockIdx.x / PCH, c = blockIdx.x % PCH;
    int t = threadIdx.x;
    int start = lower_bound_dev(batch, N_NODES, g);
    int end = lower_bound_dev(batch, N_NODES, g + 1);
    int len = end - start;
    int s0 = start + (int)(((long long)len * c) / PCH);
    int s1 = start + (int)(((long long)len * (c + 1)) / PCH);
    float acc = 0.f;
    for (int n = s0; n < s1; n++) acc += bf2f(hb[(size_t)n * HDIM + t]);
    pbuf[(size_t)blockIdx.x * HDIM + t] = acc;
}

// ---------------- head ----------------
__global__ __launch_bounds__(256) void k_head(const float* __restrict__ pbuf,
                                              const int* __restrict__ batch,
                                              const float* __restrict__ w1,
                                              const float* __restrict__ b1,
                                              const float* __restrict__ w2,
                                              const float* __restrict__ b2,
                                              float* __restrict__ out) {
    int g = blockIdx.x;
    int t = threadIdx.x;
    __shared__ float gs[512];
    __shared__ float red[256];
    float s = 0.f;
    #pragma unroll
    for (int c = 0; c < PCH; c++) s += pbuf[(size_t)(g * PCH + c) * HDIM + t];
    int start = lower_bound_dev(batch, N_NODES, g);
    int end = lower_bound_dev(batch, N_NODES, g + 1);
    float cntf = fmaxf((float)(end - start), 1.0f);
    gs[t] = s / cntf;
    gs[256 + t] = s;
    __syncthreads();
    float acc = b1[t];
    for (int k = 0; k < 512; k++) acc += gs[k] * w1[(size_t)k * HDIM + t];
    acc = fmaxf(acc, 0.f);
    red[t] = acc * w2[t];
    __syncthreads();
    for (int s2 = 128; s2 > 0; s2 >>= 1) {
        if (t < s2) red[t] += red[t + s2];
        __syncthreads();
    }
    if (t == 0) out[g] = red[0] + b2[0];
}

extern "C" void kernel_launch(void* const* d_in, const int* in_sizes, int n_in,
                              void* d_out, int out_size, void* d_ws, size_t ws_size,
                              hipStream_t stream) {
    const float* x      = (const float*)d_in[0];
    const int*   ei     = (const int*)d_in[1];
    const int*   srcIdx = ei;
    const int*   dstIdx = ei + N_EDGES;
    const int*   batch  = (const int*)d_in[2];
    const float* enc_w  = (const float*)d_in[3];
    const float* enc_b  = (const float*)d_in[4];
    const float* conv_w = (const float*)d_in[5];
    const float* conv_b = (const float*)d_in[6];
    const float* gamma  = (const float*)d_in[7];
    const float* beta   = (const float*)d_in[8];
    const float* bmean  = (const float*)d_in[9];
    const float* bvar   = (const float*)d_in[10];
    const float* w1     = (const float*)d_in[11];
    const float* b1     = (const float*)d_in[12];
    const float* w2     = (const float*)d_in[13];
    const float* b2     = (const float*)d_in[14];
    float* out = (float*)d_out;

    char* ws = (char*)d_ws;
    size_t off = 0;
    auto alloc = [&](size_t bytes) -> void* {
        void* p = ws + off;
        off = (off + bytes + 255) & ~(size_t)255;
        return p;
    };
    int*   cnt    = (int*)alloc((size_t)N_NODES * 4);
    int*   col    = (int*)alloc((size_t)N_NODES * ELLS * 4);
    u16*   hb     = (u16*)alloc((size_t)N_NODES * HDIM * 2);
    u16*   mb     = (u16*)alloc((size_t)N_NODES * HDIM * 2);
    u16*   encT   = (u16*)alloc((size_t)HDIM * IN_DIM * 2);
    u16*   convT  = (u16*)alloc((size_t)LAYERS * HDIM * HDIM * 2);
    float* bnA    = (float*)alloc((size_t)LAYERS * HDIM * 4);
    float* bnB    = (float*)alloc((size_t)LAYERS * HDIM * 4);
    float* pbuf   = (float*)alloc((size_t)N_GRAPHS * PCH * HDIM * 4);
    u16*   xb     = mb;  // xb consumed by encoder GEMM before mb is written

    const int nb_edges = (N_EDGES + 255) / 256;

    // prep (conversions + BN fold + cnt zero)
    k_prep<<<(PREP_TOTAL + 255) / 256, 256, 0, stream>>>(
        x, xb, enc_w, encT, conv_w, convT, gamma, beta, bmean, bvar, bnA, bnB, cnt);

    // ELL adjacency (cnt doubles as cursor; final value = degree)
    k_scatter_ell<<<nb_edges, 256, 0, stream>>>(srcIdx, dstIdx, cnt, col);

    // encoder -> hb (bf16 residual stream)
    dim3 gg((N_NODES + 127) / 128, HDIM / 64);
    k_gemm_mfma<IN_DIM, 0><<<gg, 256, 0, stream>>>(xb, encT, enc_b, hb, N_NODES);

    // conv layers
    for (int l = 0; l < LAYERS; l++) {
        k_gemm_mfma<HDIM, 1><<<gg, 256, 0, stream>>>(
            hb, convT + (size_t)l * HDIM * HDIM, nullptr, mb, N_NODES);
        k_aggregate<<<NBLK_AGG, 256, 0, stream>>>(
            mb, cnt, col,
            conv_b + (size_t)l * HDIM, bnA + (size_t)l * HDIM, bnB + (size_t)l * HDIM,
            hb);
    }

    // pooling + head
    k_pool_partial<<<N_GRAPHS * PCH, 256, 0, stream>>>(hb, batch, pbuf);
    k_head<<<N_GRAPHS, 256, 0, stream>>>(pbuf, batch, w1, b1, w2, b2, out);
}

// Round 13
// 200.161 us; speedup vs baseline: 1.2974x; 1.1515x over previous
//
#include <hip/hip_runtime.h>

#define N_NODES 20000
#define N_EDGES 320000
#define N_GRAPHS 128
#define IN_DIM 128
#define HDIM 256
#define LAYERS 4
#define EPSV 1e-5f
#define PCH 16
#define ELLS 64                  // ELL stride (max degree; P(deg>64) ~ 4e-14)
#define NBLK_AGG (N_NODES / 4)

#define XQ (N_NODES * IN_DIM / 4)
#define ENC_N (HDIM * IN_DIM)
#define CONV_N (LAYERS * HDIM * HDIM)
#define BN_N (LAYERS * HDIM)
#define PREP_TOTAL (XQ + ENC_N + CONV_N + BN_N + N_NODES)

typedef unsigned short u16;
typedef unsigned char u8;
typedef __attribute__((ext_vector_type(8))) __bf16 bf16x8;
typedef __attribute__((ext_vector_type(4))) float f32x4;
typedef __attribute__((ext_vector_type(2))) float f32x2;
typedef __attribute__((ext_vector_type(8))) unsigned short u16x8;

__device__ __forceinline__ u16 f2bf(float f) {
    unsigned int u = __float_as_uint(f);
    u += 0x7FFFu + ((u >> 16) & 1u);
    return (u16)(u >> 16);
}
__device__ __forceinline__ float bf2f(u16 s) {
    return __uint_as_float((unsigned int)s << 16);
}
__device__ __forceinline__ u8 f2fp8(float v) {
    return (u8)(__builtin_amdgcn_cvt_pk_fp8_f32(v, v, 0, false) & 0xff);
}
// decode 8 packed fp8 (uint2) -> 8 floats
__device__ __forceinline__ void fp8x8_to_f32(uint2 v, float* o) {
    f32x2 a0 = __builtin_amdgcn_cvt_pk_f32_fp8(v.x, false);
    f32x2 a1 = __builtin_amdgcn_cvt_pk_f32_fp8(v.x, true);
    f32x2 a2 = __builtin_amdgcn_cvt_pk_f32_fp8(v.y, false);
    f32x2 a3 = __builtin_amdgcn_cvt_pk_f32_fp8(v.y, true);
    o[0] = a0.x; o[1] = a0.y; o[2] = a1.x; o[3] = a1.y;
    o[4] = a2.x; o[5] = a2.y; o[6] = a3.x; o[7] = a3.y;
}

// ---------------- fused prep: cvt x / encT / convT, BN fold, zero cnt ----------------
__global__ __launch_bounds__(256) void k_prep(
    const float* __restrict__ x, u16* __restrict__ xb,
    const float* __restrict__ enc_w, u16* __restrict__ encT,
    const float* __restrict__ conv_w, u16* __restrict__ convT,
    const float* __restrict__ gamma, const float* __restrict__ beta,
    const float* __restrict__ mean, const float* __restrict__ var,
    float* __restrict__ bnA, float* __restrict__ bnB, int* __restrict__ cnt)
{
    int idx = blockIdx.x * 256 + threadIdx.x;
    if (idx < XQ) {
        float4 v = *reinterpret_cast<const float4*>(x + (size_t)idx * 4);
        ushort4 o;
        o.x = f2bf(v.x); o.y = f2bf(v.y); o.z = f2bf(v.z); o.w = f2bf(v.w);
        *reinterpret_cast<ushort4*>(xb + (size_t)idx * 4) = o;
        return;
    }
    idx -= XQ;
    if (idx < ENC_N) {
        int n = idx / IN_DIM, k = idx - n * IN_DIM;
        encT[idx] = f2bf(enc_w[(size_t)k * HDIM + n]);
        return;
    }
    idx -= ENC_N;
    if (idx < CONV_N) {
        int l = idx >> 16, i = idx & 65535;
        int n = i >> 8, k = i & 255;
        convT[idx] = f2bf(conv_w[((size_t)l << 16) + (size_t)k * HDIM + n]);
        return;
    }
    idx -= CONV_N;
    if (idx < BN_N) {
        float A = gamma[idx] * rsqrtf(var[idx] + EPSV);
        bnA[idx] = A;
        bnB[idx] = beta[idx] - mean[idx] * A;
        return;
    }
    idx -= BN_N;
    if (idx < N_NODES) cnt[idx] = 0;
}

// ---------------- ELL build: cnt doubles as cursor ----------------
__global__ void k_scatter_ell(const int* __restrict__ src, const int* __restrict__ dst,
                              int* __restrict__ cnt, int* __restrict__ col) {
    int e = blockIdx.x * 256 + threadIdx.x;
    if (e < N_EDGES) {
        int d = dst[e];
        int s = src[e];
        int p = atomicAdd(&cnt[d], 1);
        if (p < ELLS) col[(size_t)d * ELLS + p] = s;
    }
}

// ---------------- bf16 MFMA GEMM (128x64 tile, BK=64, counted-vmcnt pipeline) ----------------
// Grid 157x4 = 628 blocks @ 48 KB LDS -> 3 blocks/CU -> whole grid co-resident.
// Raw s_barrier is NOT a compiler memory fence: sched_barrier(0) pins on both
// sides (rule #18, verified R10).
__device__ __forceinline__ bf16x8 load_frag(const u16* __restrict__ lds, int r, int g) {
    const char* rb = (const char*)(lds + r * 32);
    int s = (r & 3) << 4;
    union { struct { unsigned long long lo, hi; } q; bf16x8 v; } u;
    u.q.lo = *(const unsigned long long*)(rb + ((g * 8) ^ s));
    u.q.hi = *(const unsigned long long*)(rb + ((32 + g * 8) ^ s));
    return u.v;
}

template <int K, int MODE>  // MODE 0: +bias -> bf16 Cb (encoder); MODE 1: -> fp8 Cf8 (conv)
__global__ __launch_bounds__(256) void k_gemm_mfma(
    const u16* __restrict__ A, const u16* __restrict__ BT,
    const float* __restrict__ bias, u16* __restrict__ Cb,
    u8* __restrict__ Cf8, int M)
{
    constexpr int NT2 = K / 64;              // BK = 64 (two 32-wide sub-tiles)
    __shared__ u16 As[2][2][128 * 32];
    __shared__ u16 Bs[2][2][64 * 32];
    const int tid = threadIdx.x;
    const int lane = tid & 63;
    const int wr = tid >> 6;                 // wave 0..3 -> row quadrant
    const int m0 = blockIdx.x * 128, n0 = blockIdx.y * 64;
    const int g = lane >> 4, lr = lane & 15;

    f32x4 acc[2][4] = {};

    // 6 global_load_lds wave-instructions per stage -> vmcnt unit = 6
    auto stage = [&](int buf, int k0) {
        #pragma unroll
        for (int kk = 0; kk < 2; kk++) {
            #pragma unroll
            for (int j = 0; j < 2; j++) {
                int q = tid + 256 * j;
                int r = q >> 2, c4 = q & 3;
                int boff = (c4 * 16) ^ ((r & 3) << 4);
                int arow = m0 + r; if (arow >= M) arow = M - 1;
                const char* ga = (const char*)(A + (size_t)arow * K + k0 + kk * 32) + boff;
                __builtin_amdgcn_global_load_lds(
                    (const __attribute__((address_space(1))) void*)ga,
                    (__attribute__((address_space(3))) void*)((char*)As[buf][kk] + q * 16),
                    16, 0, 0);
            }
            {
                int q = tid;
                int r = q >> 2, c4 = q & 3;
                int boff = (c4 * 16) ^ ((r & 3) << 4);
                const char* gb = (const char*)(BT + (size_t)(n0 + r) * K + k0 + kk * 32) + boff;
                __builtin_amdgcn_global_load_lds(
                    (const __attribute__((address_space(1))) void*)gb,
                    (__attribute__((address_space(3))) void*)((char*)Bs[buf][kk] + q * 16),
                    16, 0, 0);
            }
        }
    };

    stage(0, 0);
    #pragma unroll
    for (int kt = 0; kt < NT2; kt++) {
        const int cur = kt & 1;
        if (kt + 1 < NT2) {
            stage(cur ^ 1, (kt + 1) * 64);          // next tile's loads stay in flight
            asm volatile("s_waitcnt vmcnt(6)" ::: "memory");   // cur tile landed
        } else {
            asm volatile("s_waitcnt vmcnt(0)" ::: "memory");
        }
        __builtin_amdgcn_sched_barrier(0);
        __builtin_amdgcn_s_barrier();               // all waves: cur buf ready
        __builtin_amdgcn_sched_barrier(0);

        #pragma unroll
        for (int kk = 0; kk < 2; kk++) {
            bf16x8 af[2], bfr[4];
            #pragma unroll
            for (int mi = 0; mi < 2; mi++)
                af[mi] = load_frag(As[cur][kk], wr * 32 + mi * 16 + lr, g);
            #pragma unroll
            for (int ni = 0; ni < 4; ni++)
                bfr[ni] = load_frag(Bs[cur][kk], ni * 16 + lr, g);
            #pragma unroll
            for (int mi = 0; mi < 2; mi++)
                #pragma unroll
                for (int ni = 0; ni < 4; ni++)
                    acc[mi][ni] = __builtin_amdgcn_mfma_f32_16x16x32_bf16(
                        af[mi], bfr[ni], acc[mi][ni], 0, 0, 0);
        }

        asm volatile("s_waitcnt lgkmcnt(0)" ::: "memory");  // LDS reads retired
        __builtin_amdgcn_sched_barrier(0);
        __builtin_amdgcn_s_barrier();               // reads done before buf overwrite
        __builtin_amdgcn_sched_barrier(0);
    }

    #pragma unroll
    for (int mi = 0; mi < 2; mi++) {
        #pragma unroll
        for (int rg = 0; rg < 4; rg++) {
            int row = m0 + wr * 32 + mi * 16 + g * 4 + rg;
            if (row >= M) continue;
            #pragma unroll
            for (int ni = 0; ni < 4; ni++) {
                int colg = n0 + ni * 16 + lr;
                float v = acc[mi][ni][rg];
                if (MODE == 0) {
                    v += bias[colg];
                    Cb[(size_t)row * HDIM + colg] = f2bf(v);
                } else {
                    Cf8[(size_t)row * HDIM + colg] = f2fp8(v);
                }
            }
        }
    }
}

// ---------------- aggregate + bias + relu + bn + residual (ELL, fp8 gather) ----------------
// Messages mf8 are fp8 e4m3 (256 B/row): half the gather bytes of bf16.
// Residual chain hb stays bf16; all arithmetic fp32.
__global__ __launch_bounds__(256) void k_aggregate(
    const u8* __restrict__ mf8, const int* __restrict__ cnt,
    const int* __restrict__ col,
    const float* __restrict__ cb, const float* __restrict__ bnA,
    const float* __restrict__ bnB, u16* __restrict__ hb)
{
    const int node = blockIdx.x * 4 + (threadIdx.x >> 6);
    const int lane = threadIdx.x & 63;
    const int p = lane >> 5;
    const int c = (lane & 31) * 8;           // 8 cols (8 B of fp8) per lane
    int nb = cnt[node]; if (nb > ELLS) nb = ELLS;
    const float di = rsqrtf((float)nb + 1.0f);

    int s_l = 0; float w_l = 0.f;            // lanes >= nb: row 0, weight 0
    if (lane < nb) {
        s_l = col[(size_t)node * ELLS + lane];
        w_l = rsqrtf((float)cnt[s_l] + 1.0f) * di;
    }

    float a[8] = {};
    if (p == 0) {  // self-loop, weight di*di
        float dii = di * di;
        uint2 v = *reinterpret_cast<const uint2*>(mf8 + (size_t)node * HDIM + c);
        float f[8]; fp8x8_to_f32(v, f);
        #pragma unroll
        for (int j = 0; j < 8; j++) a[j] = dii * f[j];
    }

    const int iters = (nb + 1) >> 1;         // edge pairs (<= 32)
    for (int t = 0; t < iters; t += 8) {
        int e = 2 * t + p;
        int   s0 = __shfl(s_l, e,      64); float w0 = __shfl(w_l, e,      64);
        int   s1 = __shfl(s_l, e + 2,  64); float w1 = __shfl(w_l, e + 2,  64);
        int   s2 = __shfl(s_l, e + 4,  64); float w2 = __shfl(w_l, e + 4,  64);
        int   s3 = __shfl(s_l, e + 6,  64); float w3 = __shfl(w_l, e + 6,  64);
        int   s4 = __shfl(s_l, e + 8,  64); float w4 = __shfl(w_l, e + 8,  64);
        int   s5 = __shfl(s_l, e + 10, 64); float w5 = __shfl(w_l, e + 10, 64);
        int   s6 = __shfl(s_l, e + 12, 64); float w6 = __shfl(w_l, e + 12, 64);
        int   s7 = __shfl(s_l, e + 14, 64); float w7 = __shfl(w_l, e + 14, 64);
        uint2 v0 = *reinterpret_cast<const uint2*>(mf8 + (size_t)s0 * HDIM + c);
        uint2 v1 = *reinterpret_cast<const uint2*>(mf8 + (size_t)s1 * HDIM + c);
        uint2 v2 = *reinterpret_cast<const uint2*>(mf8 + (size_t)s2 * HDIM + c);
        uint2 v3 = *reinterpret_cast<const uint2*>(mf8 + (size_t)s3 * HDIM + c);
        uint2 v4 = *reinterpret_cast<const uint2*>(mf8 + (size_t)s4 * HDIM + c);
        uint2 v5 = *reinterpret_cast<const uint2*>(mf8 + (size_t)s5 * HDIM + c);
        uint2 v6 = *reinterpret_cast<const uint2*>(mf8 + (size_t)s6 * HDIM + c);
        uint2 v7 = *reinterpret_cast<const uint2*>(mf8 + (size_t)s7 * HDIM + c);
        float f0[8], f1[8], f2[8], f3[8], f4[8], f5[8], f6[8], f7[8];
        fp8x8_to_f32(v0, f0); fp8x8_to_f32(v1, f1);
        fp8x8_to_f32(v2, f2); fp8x8_to_f32(v3, f3);
        fp8x8_to_f32(v4, f4); fp8x8_to_f32(v5, f5);
        fp8x8_to_f32(v6, f6); fp8x8_to_f32(v7, f7);
        #pragma unroll
        for (int j = 0; j < 8; j++) {
            a[j] += w0 * f0[j] + w1 * f1[j];
            a[j] += w2 * f2[j] + w3 * f3[j];
            a[j] += w4 * f4[j] + w5 * f5[j];
            a[j] += w6 * f6[j] + w7 * f7[j];
        }
    }

    #pragma unroll
    for (int j = 0; j < 8; j++) a[j] += __shfl_xor(a[j], 32, 64);

    if (p == 0) {
        const size_t base = (size_t)node * HDIM + c;
        u16x8 rv = *reinterpret_cast<const u16x8*>(hb + base);   // residual (bf16)
        float4 cb0 = *reinterpret_cast<const float4*>(cb + c);
        float4 cb1 = *reinterpret_cast<const float4*>(cb + c + 4);
        float4 A0 = *reinterpret_cast<const float4*>(bnA + c);
        float4 A1 = *reinterpret_cast<const float4*>(bnA + c + 4);
        float4 B0 = *reinterpret_cast<const float4*>(bnB + c);
        float4 B1 = *reinterpret_cast<const float4*>(bnB + c + 4);
        float cbv[8] = {cb0.x, cb0.y, cb0.z, cb0.w, cb1.x, cb1.y, cb1.z, cb1.w};
        float Av[8] = {A0.x, A0.y, A0.z, A0.w, A1.x, A1.y, A1.z, A1.w};
        float Bv[8] = {B0.x, B0.y, B0.z, B0.w, B1.x, B1.y, B1.z, B1.w};
        u16x8 hbv;
        #pragma unroll
        for (int j = 0; j < 8; j++) {
            float v = fmaxf(a[j] + cbv[j], 0.f);
            hbv[j] = f2bf(bf2f(rv[j]) + v * Av[j] + Bv[j]);
        }
        *reinterpret_cast<u16x8*>(hb + base) = hbv;
    }
}

// ---------------- pooling: stage 1 partial sums (bf16 input) ----------------
__device__ __forceinline__ int lower_bound_dev(const int* a, int n, int key) {
    int lo = 0, hi = n;
    while (lo < hi) {
        int mid = (lo + hi) >> 1;
        if (a[mid] < key) lo = mid + 1; else hi = mid;
    }
    return lo;
}

__global__ __launch_bounds__(256) void k_pool_partial(const u16* __restrict__ hb,
                                                      const int* __restrict__ batch,
                                                      float* __restrict__ pbuf) {
    int g = blockIdx.x / PCH, c = blockIdx.x % PCH;
    int t = threadIdx.x;
    int start = lower_bound_dev(batch, N_NODES, g);
    int end = lower_bound_dev(batch, N_NODES, g + 1);
    int len = end - start;
    int s0 = start + (int)(((long long)len * c) / PCH);
    int s1 = start + (int)(((long long)len * (c + 1)) / PCH);
    float acc = 0.f;
    for (int n = s0; n < s1; n++) acc += bf2f(hb[(size_t)n * HDIM + t]);
    pbuf[(size_t)blockIdx.x * HDIM + t] = acc;
}

// ---------------- head ----------------
__global__ __launch_bounds__(256) void k_head(const float* __restrict__ pbuf,
                                              const int* __restrict__ batch,
                                              const float* __restrict__ w1,
                                              const float* __restrict__ b1,
                                              const float* __restrict__ w2,
                                              const float* __restrict__ b2,
                                              float* __restrict__ out) {
    int g = blockIdx.x;
    int t = threadIdx.x;
    __shared__ float gs[512];
    __shared__ float red[256];
    float s = 0.f;
    #pragma unroll
    for (int c = 0; c < PCH; c++) s += pbuf[(size_t)(g * PCH + c) * HDIM + t];
    int start = lower_bound_dev(batch, N_NODES, g);
    int end = lower_bound_dev(batch, N_NODES, g + 1);
    float cntf = fmaxf((float)(end - start), 1.0f);
    gs[t] = s / cntf;
    gs[256 + t] = s;
    __syncthreads();
    float acc = b1[t];
    for (int k = 0; k < 512; k++) acc += gs[k] * w1[(size_t)k * HDIM + t];
    acc = fmaxf(acc, 0.f);
    red[t] = acc * w2[t];
    __syncthreads();
    for (int s2 = 128; s2 > 0; s2 >>= 1) {
        if (t < s2) red[t] += red[t + s2];
        __syncthreads();
    }
    if (t == 0) out[g] = red[0] + b2[0];
}

extern "C" void kernel_launch(void* const* d_in, const int* in_sizes, int n_in,
                              void* d_out, int out_size, void* d_ws, size_t ws_size,
                              hipStream_t stream) {
    const float* x      = (const float*)d_in[0];
    const int*   ei     = (const int*)d_in[1];
    const int*   srcIdx = ei;
    const int*   dstIdx = ei + N_EDGES;
    const int*   batch  = (const int*)d_in[2];
    const float* enc_w  = (const float*)d_in[3];
    const float* enc_b  = (const float*)d_in[4];
    const float* conv_w = (const float*)d_in[5];
    const float* conv_b = (const float*)d_in[6];
    const float* gamma  = (const float*)d_in[7];
    const float* beta   = (const float*)d_in[8];
    const float* bmean  = (const float*)d_in[9];
    const float* bvar   = (const float*)d_in[10];
    const float* w1     = (const float*)d_in[11];
    const float* b1     = (const float*)d_in[12];
    const float* w2     = (const float*)d_in[13];
    const float* b2     = (const float*)d_in[14];
    float* out = (float*)d_out;

    char* ws = (char*)d_ws;
    size_t off = 0;
    auto alloc = [&](size_t bytes) -> void* {
        void* p = ws + off;
        off = (off + bytes + 255) & ~(size_t)255;
        return p;
    };
    int*   cnt    = (int*)alloc((size_t)N_NODES * 4);
    int*   col    = (int*)alloc((size_t)N_NODES * ELLS * 4);
    u16*   hb     = (u16*)alloc((size_t)N_NODES * HDIM * 2);
    u8*    mf8    = (u8*)alloc((size_t)N_NODES * HDIM * 1);  // fp8 messages; aliased as xb
    u16*   encT   = (u16*)alloc((size_t)HDIM * IN_DIM * 2);
    u16*   convT  = (u16*)alloc((size_t)LAYERS * HDIM * HDIM * 2);
    float* bnA    = (float*)alloc((size_t)LAYERS * HDIM * 4);
    float* bnB    = (float*)alloc((size_t)LAYERS * HDIM * 4);
    float* pbuf   = (float*)alloc((size_t)N_GRAPHS * PCH * HDIM * 4);
    u16*   xb     = (u16*)mf8;  // bf16 x (5 MB) == fp8 mb (5 MB); xb consumed by
                                // encoder GEMM before first conv writes mf8

    const int nb_edges = (N_EDGES + 255) / 256;

    // prep (conversions + BN fold + cnt zero)
    k_prep<<<(PREP_TOTAL + 255) / 256, 256, 0, stream>>>(
        x, xb, enc_w, encT, conv_w, convT, gamma, beta, bmean, bvar, bnA, bnB, cnt);

    // ELL adjacency (cnt doubles as cursor; final value = degree)
    k_scatter_ell<<<nb_edges, 256, 0, stream>>>(srcIdx, dstIdx, cnt, col);

    // encoder -> hb (bf16 residual stream)
    dim3 gg((N_NODES + 127) / 128, HDIM / 64);
    k_gemm_mfma<IN_DIM, 0><<<gg, 256, 0, stream>>>(xb, encT, enc_b, hb, nullptr, N_NODES);

    // conv layers (messages in fp8)
    for (int l = 0; l < LAYERS; l++) {
        k_gemm_mfma<HDIM, 1><<<gg, 256, 0, stream>>>(
            hb, convT + (size_t)l * HDIM * HDIM, nullptr, nullptr, mf8, N_NODES);
        k_aggregate<<<NBLK_AGG, 256, 0, stream>>>(
            mf8, cnt, col,
            conv_b + (size_t)l * HDIM, bnA + (size_t)l * HDIM, bnB + (size_t)l * HDIM,
            hb);
    }

    // pooling + head
    k_pool_partial<<<N_GRAPHS * PCH, 256, 0, stream>>>(hb, batch, pbuf);
    k_head<<<N_GRAPHS, 256, 0, stream>>>(pbuf, batch, w1, b1, w2, b2, out);
}